// Round 1
// baseline (7224.665 us; speedup 1.0000x reference)
//
#include <hip/hip_runtime.h>
#include <cmath>

// LSTM decode: B=64, H=2048, steps=30 (steps derived from out_size at runtime).
// Key identity: feedback input x_{t+1} == h_{t+1}, so gates = h @ (W_ih+W_hh)^T + (b_ih+b_hh)
// for t>=1; t==0 has x=0 -> only W_hh. Precompute W_sum once per launch.
// h is kept TRANSPOSED in workspace: hT[k][b] (k=hidden idx, b=batch) so that
//  - per-step LDS staging is a flat contiguous coalesced copy
//  - the h_out write from the pointwise stage is coalesced (lanes = batch).

#define HID   2048
#define BATCH 64
#define G4    (4 * HID)
#define KT    256            // K-tile staged in LDS: KT*BATCH*4 = 64 KB exactly
#define JPB   4              // hidden units per block (one per wave)
#define NB    (HID / JPB)    // 512 blocks per step kernel

// ---- W_sum = W_ih + W_hh (may run in-place with o==a; element-wise safe) ----
__global__ void k_wsum(const float4* a, const float4* b, float4* o, int n4) {
    int i = blockIdx.x * blockDim.x + threadIdx.x;
    if (i < n4) {
        float4 x = a[i], y = b[i];
        o[i] = make_float4(x.x + y.x, x.y + y.y, x.z + y.z, x.w + y.w);
    }
}

// ---- init: hT0 = transpose(token), c = 0, bsum = b_ih + b_hh ----
__global__ void k_init(const float* __restrict__ token, const float* __restrict__ bih,
                       const float* __restrict__ bhh, float* __restrict__ hT,
                       float* __restrict__ c, float* __restrict__ bsum) {
    int i = blockIdx.x * blockDim.x + threadIdx.x;
    if (i < BATCH * HID) {
        int b = i & 63;
        int k = i >> 6;
        hT[i] = token[(size_t)b * HID + k];   // write coalesced, read is a one-time gather
        c[i]  = 0.0f;
    }
    if (i < G4) bsum[i] = bih[i] + bhh[i];
}

// ---- one LSTM step, fused: gates GEMM + nonlinearity + c/h update + y partial ----
// grid = NB(512) blocks, block = 256 threads = 64 batch lanes x 4 hidden units (1/wave).
__global__ __launch_bounds__(256, 2)
void k_step(const float* __restrict__ W,      // (4H, H) row-major: W_sum (or W_hh at t=0)
            const float* __restrict__ bsum,   // (4H)
            const float* __restrict__ hT_in,  // [H][B] transposed hidden
            float* __restrict__ c,            // [H][B] transposed cell, in-place
            float* __restrict__ hT_out,       // [H][B]
            const float* __restrict__ wout,   // (H)
            float* __restrict__ ypart)        // [NB][B] per-block partial y for this t
{
    __shared__ float sh[KT * BATCH];          // [k][b], 64 KB -> 2 blocks/CU
    const int tid = threadIdx.x;
    const int b   = tid & 63;                 // lane = batch index
    int j = blockIdx.x * JPB + (tid >> 6);    // hidden unit, uniform per wave
    j = __builtin_amdgcn_readfirstlane(j);    // force scalar weight addressing (s_load)

    const float* w0 = W + (size_t)(0 * HID + j) * HID;  // i gate row
    const float* w1 = W + (size_t)(1 * HID + j) * HID;  // f
    const float* w2 = W + (size_t)(2 * HID + j) * HID;  // g
    const float* w3 = W + (size_t)(3 * HID + j) * HID;  // o

    float ai = 0.f, af = 0.f, ag = 0.f, ao = 0.f;

    for (int k0 = 0; k0 < HID; k0 += KT) {
        // flat contiguous 64 KB copy: global (coalesced float4) -> LDS (conflict-free)
        const float4* src = (const float4*)(hT_in + (size_t)k0 * BATCH);
        float4* dst = (float4*)sh;
        #pragma unroll
        for (int it = 0; it < (KT * BATCH / 4) / 256; ++it)   // 16 iters
            dst[tid + it * 256] = src[tid + it * 256];
        __syncthreads();

        #pragma unroll 8
        for (int k = 0; k < KT; ++k) {
            float hv = sh[k * BATCH + b];     // lanes read consecutive addrs: conflict-free
            int kk = k0 + k;
            ai = fmaf(hv, w0[kk], ai);
            af = fmaf(hv, w1[kk], af);
            ag = fmaf(hv, w2[kk], ag);
            ao = fmaf(hv, w3[kk], ao);
        }
        __syncthreads();
    }

    ai += bsum[j];
    af += bsum[HID + j];
    ag += bsum[2 * HID + j];
    ao += bsum[3 * HID + j];

    float iv = 1.0f / (1.0f + expf(-ai));
    float fv = 1.0f / (1.0f + expf(-af));
    float gv = tanhf(ag);
    float ov = 1.0f / (1.0f + expf(-ao));

    size_t cidx = (size_t)j * BATCH + b;      // transposed layout -> coalesced
    float cnew = fv * c[cidx] + iv * gv;
    float hnew = ov * tanhf(cnew);
    c[cidx]      = cnew;
    hT_out[cidx] = hnew;

    // per-block partial of y[b] = sum_j hnew(b,j) * wout[j]; reuse sh (safe: all waves
    // passed the loop-trailing __syncthreads and no one reads k-data anymore)
    sh[(tid >> 6) * BATCH + b] = hnew * wout[j];
    __syncthreads();
    if (tid < BATCH) {
        float p = sh[b] + sh[BATCH + b] + sh[2 * BATCH + b] + sh[3 * BATCH + b];
        ypart[blockIdx.x * BATCH + b] = p;
    }
}

// ---- final: out[b][t] = b_out + sum over NB partials ----
__global__ void k_out(const float* __restrict__ ypart, const float* __restrict__ bout,
                      float* __restrict__ out, int steps) {
    int i = blockIdx.x * blockDim.x + threadIdx.x;
    if (i >= BATCH * steps) return;
    int b = i / steps;
    int t = i - b * steps;
    const float* p = ypart + (size_t)t * NB * BATCH + b;
    float s = bout[0];
    #pragma unroll 4
    for (int q = 0; q < NB; ++q) s += p[(size_t)q * BATCH];
    out[i] = s;
}

extern "C" void kernel_launch(void* const* d_in, const int* in_sizes, int n_in,
                              void* d_out, int out_size, void* d_ws, size_t ws_size,
                              hipStream_t stream) {
    const float* token = (const float*)d_in[0];
    // d_in[1] = steps (device scalar) -- derived host-side from out_size instead
    const float* wih  = (const float*)d_in[2];
    const float* whh  = (const float*)d_in[3];
    const float* bih  = (const float*)d_in[4];
    const float* bhh  = (const float*)d_in[5];
    const float* wout = (const float*)d_in[6];
    const float* bout = (const float*)d_in[7];
    float* out = (float*)d_out;

    const int steps = out_size / BATCH;   // 1920/64 = 30

    char* ws = (char*)d_ws;
    size_t off = 0;
    auto carve = [&](size_t bytes) -> float* {
        float* p = (float*)(ws + off);
        off = (off + bytes + 255) & ~(size_t)255;
        return p;
    };
    float* hA    = carve((size_t)BATCH * HID * 4);
    float* hB    = carve((size_t)BATCH * HID * 4);
    float* c     = carve((size_t)BATCH * HID * 4);
    float* bsum  = carve((size_t)G4 * 4);
    float* ypart = carve((size_t)steps * NB * BATCH * 4);

    const size_t wsum_bytes = (size_t)G4 * HID * 4;   // 64 MB
    float* wsum;
    if (off + wsum_bytes <= ws_size) {
        wsum = carve(wsum_bytes);
    } else {
        // Fallback: in-place W_ih += W_hh. Safe: harness restores d_in from a
        // pristine copy before EVERY launch, and element-wise add is race-free.
        wsum = (float*)d_in[2];
    }

    const int n4 = (G4 * HID) / 4;   // 4,194,304 float4s
    k_wsum<<<dim3((n4 + 255) / 256), dim3(256), 0, stream>>>(
        (const float4*)wih, (const float4*)whh, (float4*)wsum, n4);

    k_init<<<dim3((BATCH * HID + 255) / 256), dim3(256), 0, stream>>>(
        token, bih, bhh, hA, c, bsum);

    float* hin = hA;
    float* hout = hB;
    for (int t = 0; t < steps; ++t) {
        const float* W = (t == 0) ? whh : wsum;   // step 0: x=0, only W_hh contributes
        k_step<<<dim3(NB), dim3(256), 0, stream>>>(
            W, bsum, hin, c, hout, wout, ypart + (size_t)t * NB * BATCH);
        float* tmp = hin; hin = hout; hout = tmp;
    }

    k_out<<<dim3((BATCH * steps + 255) / 256), dim3(256), 0, stream>>>(
        ypart, bout, out, steps);
}

// Round 2
// 746.015 us; speedup vs baseline: 9.6843x; 9.6843x over previous
//
#include <hip/hip_runtime.h>
#include <cmath>

// LSTM decode B=64, H=2048, steps=30. gates = W_sum @ h for t>=1 (x_t == h_t),
// W_hh @ h0 for t=0. Strategy: one-time pack of W_sum/W_hh into fp16 MFMA
// A-fragment layout, per-step MFMA GEMM (no LDS, pure streaming) + fused
// pointwise, y computed once at the end from stored h history.

#define HID   2048
#define BATCH 64
#define G4    (4 * HID)          // 8192 gate rows
#define NMT   512                // G4/16 m-tiles
#define NKT   64                 // HID/32 k-tiles
#define HGRP  (HID * BATCH / 8)  // 16384 half8 groups per h slot

typedef __attribute__((ext_vector_type(8))) _Float16 half8;
typedef __attribute__((ext_vector_type(4))) float f32x4;

// ---- one-time: pack W_sum and W_hh (fp32 row-major) to fp16 fragment layout ----
// packed[(mt*64+kt)*64+lane] = 8 f16: row j=mt*16+(lane&15), k=kt*32+(lane>>4)*8+e
__global__ void k_pack_w(const float* __restrict__ wih, const float* __restrict__ whh,
                         half8* __restrict__ wsum_p, half8* __restrict__ whh_p) {
    int g = blockIdx.x * 256 + threadIdx.x;          // [0, 512*64*64)
    int l = g & 63, kt = (g >> 6) & 63, mt = g >> 12;
    int j = mt * 16 + (l & 15);
    int k0 = kt * 32 + (l >> 4) * 8;
    const float4* pi = (const float4*)(wih + (size_t)j * HID + k0);
    const float4* ph = (const float4*)(whh + (size_t)j * HID + k0);
    float4 i0 = pi[0], i1 = pi[1], h0 = ph[0], h1 = ph[1];
    half8 s, hh;
    s[0]=(_Float16)(i0.x+h0.x); s[1]=(_Float16)(i0.y+h0.y);
    s[2]=(_Float16)(i0.z+h0.z); s[3]=(_Float16)(i0.w+h0.w);
    s[4]=(_Float16)(i1.x+h1.x); s[5]=(_Float16)(i1.y+h1.y);
    s[6]=(_Float16)(i1.z+h1.z); s[7]=(_Float16)(i1.w+h1.w);
    hh[0]=(_Float16)h0.x; hh[1]=(_Float16)h0.y; hh[2]=(_Float16)h0.z; hh[3]=(_Float16)h0.w;
    hh[4]=(_Float16)h1.x; hh[5]=(_Float16)h1.y; hh[6]=(_Float16)h1.z; hh[7]=(_Float16)h1.w;
    wsum_p[g] = s;
    whh_p[g]  = hh;
}

// ---- init: pack token -> h slot 0 (B-fragment layout), zero c, bsum ----
// h packed[(kt*4+nt)*64+lane] : n=nt*16+(lane&15), k=kt*32+(lane>>4)*8+e
__global__ void k_init(const float* __restrict__ token, const float* __restrict__ bih,
                       const float* __restrict__ bhh, half8* __restrict__ h0p,
                       float* __restrict__ c, float* __restrict__ bsum) {
    int g = blockIdx.x * 256 + threadIdx.x;          // [0, 16384)
    int l = g & 63, nt = (g >> 6) & 3, kt = g >> 8;
    int n = nt * 16 + (l & 15);
    int k0 = kt * 32 + (l >> 4) * 8;
    const float4* ps = (const float4*)(token + (size_t)n * HID + k0);
    float4 a = ps[0], b = ps[1];
    half8 v;
    v[0]=(_Float16)a.x; v[1]=(_Float16)a.y; v[2]=(_Float16)a.z; v[3]=(_Float16)a.w;
    v[4]=(_Float16)b.x; v[5]=(_Float16)b.y; v[6]=(_Float16)b.z; v[7]=(_Float16)b.w;
    h0p[g] = v;
    float4* cz = (float4*)(c + (size_t)g * 8);
    cz[0] = make_float4(0,0,0,0);
    cz[1] = make_float4(0,0,0,0);
    if (g < G4) bsum[g] = bih[g] + bhh[g];
}

// ---- per-step GEMM: partial[ks][j][b] = sum_{k in split} W[j][k] h[k][b] ----
// grid (128, KS), 256 thr = 4 waves; wave handles m-tile of 16 rows, full N=64.
__global__ __launch_bounds__(256)
void k_gemm(const half8* __restrict__ Wp, const half8* __restrict__ Hp,
            float* __restrict__ partial, int ktper) {
    const int lane = threadIdx.x & 63;
    const int wv = threadIdx.x >> 6;
    const int mt = blockIdx.x * 4 + wv;              // [0,512)
    const int ks = blockIdx.y;
    f32x4 acc0 = {0,0,0,0}, acc1 = {0,0,0,0}, acc2 = {0,0,0,0}, acc3 = {0,0,0,0};
    const half8* ap = Wp + ((size_t)mt * NKT + (size_t)ks * ktper) * 64 + lane;
    const half8* bp = Hp + (size_t)ks * ktper * 256 + lane;
    for (int kt = 0; kt < ktper; ++kt) {
        half8 a  = ap[0];
        half8 b0 = bp[0], b1 = bp[64], b2 = bp[128], b3 = bp[192];
        acc0 = __builtin_amdgcn_mfma_f32_16x16x32_f16(a, b0, acc0, 0, 0, 0);
        acc1 = __builtin_amdgcn_mfma_f32_16x16x32_f16(a, b1, acc1, 0, 0, 0);
        acc2 = __builtin_amdgcn_mfma_f32_16x16x32_f16(a, b2, acc2, 0, 0, 0);
        acc3 = __builtin_amdgcn_mfma_f32_16x16x32_f16(a, b3, acc3, 0, 0, 0);
        ap += 64;
        bp += 256;
    }
    // D layout: row m = (lane>>4)*4 + r, col n = lane&15
    const int q = lane >> 4, col = lane & 15;
    float* out = partial + ((size_t)ks * G4 + mt * 16 + q * 4) * BATCH + col;
    #pragma unroll
    for (int r = 0; r < 4; ++r) {
        out[(size_t)r * BATCH + 0 * 16] = acc0[r];
        out[(size_t)r * BATCH + 1 * 16] = acc1[r];
        out[(size_t)r * BATCH + 2 * 16] = acc2[r];
        out[(size_t)r * BATCH + 3 * 16] = acc3[r];
    }
}

// ---- per-step pointwise: gates -> c,h update; h packed fp16 for next step ----
__global__ __launch_bounds__(256)
void k_point(const float* __restrict__ partial, const float* __restrict__ bsum,
             float* __restrict__ c, _Float16* __restrict__ hnext, int ksn) {
    int g = blockIdx.x * 256 + threadIdx.x;          // [0, 131072)
    int b = g & 63, u = g >> 6;                      // u in [0,2048)
    float gi = bsum[u], gf = bsum[HID + u], gg = bsum[2 * HID + u], go = bsum[3 * HID + u];
    for (int ks = 0; ks < ksn; ++ks) {
        const float* p = partial + (size_t)ks * G4 * BATCH + b;
        gi += p[(size_t)(0 * HID + u) * BATCH];
        gf += p[(size_t)(1 * HID + u) * BATCH];
        gg += p[(size_t)(2 * HID + u) * BATCH];
        go += p[(size_t)(3 * HID + u) * BATCH];
    }
    float iv = 1.0f / (1.0f + __expf(-gi));
    float fv = 1.0f / (1.0f + __expf(-gf));
    float gv = tanhf(gg);
    float ov = 1.0f / (1.0f + __expf(-go));
    float cn = fv * c[g] + iv * gv;
    c[g] = cn;
    float hv = ov * tanhf(cn);
    // pack: k=u -> kt=u>>5, quad=(u&31)>>3, e=u&7; n=b -> nt=b>>4, lane=quad*16+(b&15)
    int kt = u >> 5, quad = (u & 31) >> 3, e = u & 7;
    int nt = b >> 4, lane = quad * 16 + (b & 15);
    hnext[((size_t)(kt * 4 + nt) * 64 + lane) * 8 + e] = (_Float16)hv;
}

// ---- final: out[b][t] = bout + sum_k h_{t+1}[k][b] * wout[k] ----
__global__ __launch_bounds__(256)
void k_yout(const half8* __restrict__ h_all, const float* __restrict__ wout,
            const float* __restrict__ bout, float* __restrict__ out, int steps) {
    __shared__ float red[256];
    int t = blockIdx.x >> 6, b = blockIdx.x & 63;
    int tid = threadIdx.x;
    int kt = tid >> 2, quad = tid & 3;
    int nt = b >> 4, lane = quad * 16 + (b & 15);
    half8 hv = h_all[(size_t)(t + 1) * HGRP + (size_t)(kt * 4 + nt) * 64 + lane];
    int k0 = kt * 32 + quad * 8;
    const float4* pw = (const float4*)(wout + k0);
    float4 w0 = pw[0], w1 = pw[1];
    float s = (float)hv[0] * w0.x + (float)hv[1] * w0.y + (float)hv[2] * w0.z +
              (float)hv[3] * w0.w + (float)hv[4] * w1.x + (float)hv[5] * w1.y +
              (float)hv[6] * w1.z + (float)hv[7] * w1.w;
    red[tid] = s;
    __syncthreads();
    for (int st = 128; st > 0; st >>= 1) {
        if (tid < st) red[tid] += red[tid + st];
        __syncthreads();
    }
    if (tid == 0) out[(size_t)b * steps + t] = red[0] + bout[0];
}

extern "C" void kernel_launch(void* const* d_in, const int* in_sizes, int n_in,
                              void* d_out, int out_size, void* d_ws, size_t ws_size,
                              hipStream_t stream) {
    const float* token = (const float*)d_in[0];
    const float* wih   = (const float*)d_in[2];
    const float* whh   = (const float*)d_in[3];
    const float* bih   = (const float*)d_in[4];
    const float* bhh   = (const float*)d_in[5];
    const float* wout  = (const float*)d_in[6];
    const float* bout  = (const float*)d_in[7];
    float* out = (float*)d_out;
    const int steps = out_size / BATCH;              // 30

    char* ws = (char*)d_ws;
    size_t off = 0;
    auto carve = [&](size_t bytes) -> void* {
        void* p = ws + off;
        off = (off + bytes + 255) & ~(size_t)255;
        return p;
    };
    half8*    wsum_p = (half8*)carve((size_t)G4 * HID * 2);          // 33.5 MB
    half8*    whh_p  = (half8*)carve((size_t)G4 * HID * 2);          // 33.5 MB
    half8*    h_all  = (half8*)carve((size_t)(steps + 1) * HID * BATCH * 2); // 8 MB
    float*    c      = (float*)carve((size_t)HID * BATCH * 4);       // 512 KB
    float*    bsum   = (float*)carve((size_t)G4 * 4);
    size_t base = off;
    int KS = 8;                                      // k-split
    while (KS > 1 && base + (size_t)KS * G4 * BATCH * 4 > ws_size) KS >>= 1;
    float* partial = (float*)carve((size_t)KS * G4 * BATCH * 4);     // 16 MB @ KS=8
    const int ktper = NKT / KS;

    k_pack_w<<<dim3(NMT * NKT * 64 / 256), dim3(256), 0, stream>>>(
        wih, whh, wsum_p, whh_p);
    k_init<<<dim3(HGRP / 256), dim3(256), 0, stream>>>(
        token, bih, bhh, h_all, c, bsum);

    for (int t = 0; t < steps; ++t) {
        const half8* Wp = (t == 0) ? whh_p : wsum_p;  // x=0 at t=0
        const half8* Hp = h_all + (size_t)t * HGRP;
        _Float16* hnext = (_Float16*)h_all + (size_t)(t + 1) * HID * BATCH;
        k_gemm<<<dim3(NMT / 4, KS), dim3(256), 0, stream>>>(Wp, Hp, partial, ktper);
        k_point<<<dim3(HID * BATCH / 256), dim3(256), 0, stream>>>(
            partial, bsum, c, hnext, KS);
    }

    k_yout<<<dim3(steps * BATCH), dim3(256), 0, stream>>>(
        h_all, wout, bout, out, steps);
}

// Round 3
// 634.271 us; speedup vs baseline: 11.3905x; 1.1762x over previous
//
#include <hip/hip_runtime.h>
#include <cmath>

// LSTM decode B=64, H=2048, steps=30. gates = W_sum @ h for t>=1 (x_t == h_t),
// W_hh @ h0 for t=0. One-time pack of W_sum/W_hh into fp16 MFMA A-fragment
// layout (LDS-transposed, both sides coalesced); per-step: streaming MFMA GEMM
// (1 a-load + 1 b-load + 1 MFMA per iter per wave, unroll 8, KS=2 k-split,
// 16 waves/CU) + fused pointwise; y computed once at the end.

#define HID   2048
#define BATCH 64
#define G4    (4 * HID)          // 8192 gate rows
#define NMT   512                // G4/16 m-tiles
#define NKT   64                 // HID/32 k-tiles
#define HGRP  (HID * BATCH / 8)  // 16384 half8 groups per h slot

typedef __attribute__((ext_vector_type(8))) _Float16 half8;
typedef __attribute__((ext_vector_type(4))) float f32x4;

// ---- one-time: pack W_sum / W_hh to fp16 A-fragment layout ----
// packed[(mt*64+kt)*64+lane] = 8 f16: row j=mt*16+(lane&15), k=kt*32+(lane>>4)*8+e
// LDS-staged: phase 1 coalesced row reads -> LDS; phase 2 fragment gather ->
// coalesced 16 B writes.
#define PKK 128
__global__ __launch_bounds__(256)
void k_pack_w(const float* __restrict__ wih, const float* __restrict__ whh,
              half8* __restrict__ wsum_p, half8* __restrict__ whh_p) {
    __shared__ _Float16 s_s[16][PKK + 8];   // +8 fp16 pad keeps rows 16B-aligned
    __shared__ _Float16 s_h[16][PKK + 8];
    const int t  = threadIdx.x;
    const int mt = blockIdx.x;              // 0..511
    const int kb = blockIdx.y;              // 0..15
    {   // phase 1: 16 rows x 128 k, coalesced 32 B per thread per matrix
        const int row = t >> 4;
        const int kc  = (t & 15) * 8;
        const size_t base = (size_t)(mt * 16 + row) * HID + kb * PKK + kc;
        const float4* pi = (const float4*)(wih + base);
        const float4* ph = (const float4*)(whh + base);
        float4 i0 = pi[0], i1 = pi[1], h0 = ph[0], h1 = ph[1];
        _Float16* ds = &s_s[row][kc];
        _Float16* dh = &s_h[row][kc];
        ds[0]=(_Float16)(i0.x+h0.x); ds[1]=(_Float16)(i0.y+h0.y);
        ds[2]=(_Float16)(i0.z+h0.z); ds[3]=(_Float16)(i0.w+h0.w);
        ds[4]=(_Float16)(i1.x+h1.x); ds[5]=(_Float16)(i1.y+h1.y);
        ds[6]=(_Float16)(i1.z+h1.z); ds[7]=(_Float16)(i1.w+h1.w);
        dh[0]=(_Float16)h0.x; dh[1]=(_Float16)h0.y; dh[2]=(_Float16)h0.z; dh[3]=(_Float16)h0.w;
        dh[4]=(_Float16)h1.x; dh[5]=(_Float16)h1.y; dh[6]=(_Float16)h1.z; dh[7]=(_Float16)h1.w;
    }
    __syncthreads();
    // phase 2: each thread emits one half8 per matrix, writes coalesced
    const int ktl  = t >> 6;                // 0..3  (k-tile within this 128-k block)
    const int lane = t & 63;
    const int row  = lane & 15;
    const int kq   = ktl * 32 + (lane >> 4) * 8;
    half8 vs, vh;
    #pragma unroll
    for (int e = 0; e < 8; ++e) { vs[e] = s_s[row][kq + e]; vh[e] = s_h[row][kq + e]; }
    size_t g = ((size_t)mt * 64 + (kb * 4 + ktl)) * 64 + lane;
    wsum_p[g] = vs;
    whh_p[g]  = vh;
}

// ---- init: pack token -> h slot 0 (B-fragment layout), zero c, bsum ----
// h packed[(kt*4+nt)*64+lane] : n=nt*16+(lane&15), k=kt*32+(lane>>4)*8+e
__global__ void k_init(const float* __restrict__ token, const float* __restrict__ bih,
                       const float* __restrict__ bhh, half8* __restrict__ h0p,
                       float* __restrict__ c, float* __restrict__ bsum) {
    int g = blockIdx.x * 256 + threadIdx.x;          // [0, 16384)
    int l = g & 63, nt = (g >> 6) & 3, kt = g >> 8;
    int n = nt * 16 + (l & 15);
    int k0 = kt * 32 + (l >> 4) * 8;
    const float4* ps = (const float4*)(token + (size_t)n * HID + k0);
    float4 a = ps[0], b = ps[1];
    half8 v;
    v[0]=(_Float16)a.x; v[1]=(_Float16)a.y; v[2]=(_Float16)a.z; v[3]=(_Float16)a.w;
    v[4]=(_Float16)b.x; v[5]=(_Float16)b.y; v[6]=(_Float16)b.z; v[7]=(_Float16)b.w;
    h0p[g] = v;
    float4* cz = (float4*)(c + (size_t)g * 8);
    cz[0] = make_float4(0,0,0,0);
    cz[1] = make_float4(0,0,0,0);
    if (g < G4) bsum[g] = bih[g] + bhh[g];
}

// ---- per-step GEMM: partial[ks][row][b] over the ks half of K ----
// grid (NMT, KS); block 256 = 4 waves, wave = one n-tile of the same m-tile.
// Per iter: 1 a-load (shared stream across the 4 waves -> L1) + 1 b-load + 1 MFMA.
__global__ __launch_bounds__(256, 4)
void k_gemm(const half8* __restrict__ Wp, const half8* __restrict__ Hp,
            float* __restrict__ partial, int ktper) {
    const int lane = threadIdx.x & 63;
    const int nt   = threadIdx.x >> 6;               // n-tile 0..3
    const int mt   = blockIdx.x;                     // 0..511
    const int ks   = blockIdx.y;
    f32x4 acc = {0, 0, 0, 0};
    const half8* ap = Wp + ((size_t)mt * NKT + (size_t)ks * ktper) * 64 + lane;
    const half8* bp = Hp + ((size_t)(ks * ktper) * 4 + nt) * 64 + lane;
    #pragma unroll 8
    for (int kt = 0; kt < ktper; ++kt) {
        half8 a = ap[(size_t)kt * 64];
        half8 b = bp[(size_t)kt * 256];
        acc = __builtin_amdgcn_mfma_f32_16x16x32_f16(a, b, acc, 0, 0, 0);
    }
    // D layout: row m = (lane>>4)*4 + r, col n = lane&15
    const int q = lane >> 4, col = lane & 15;
    float* out = partial + ((size_t)ks * G4 + mt * 16 + q * 4) * BATCH + nt * 16 + col;
    #pragma unroll
    for (int r = 0; r < 4; ++r) out[(size_t)r * BATCH] = acc[r];
}

// ---- per-step pointwise: gates -> c,h update; h packed fp16 for next step ----
__global__ __launch_bounds__(256)
void k_point(const float* __restrict__ partial, const float* __restrict__ bsum,
             float* __restrict__ c, _Float16* __restrict__ hnext, int ksn) {
    int g = blockIdx.x * 256 + threadIdx.x;          // [0, 131072)
    int b = g & 63, u = g >> 6;                      // u in [0,2048)
    float gi = bsum[u], gf = bsum[HID + u], gg = bsum[2 * HID + u], go = bsum[3 * HID + u];
    for (int ks = 0; ks < ksn; ++ks) {
        const float* p = partial + (size_t)ks * G4 * BATCH + b;
        gi += p[(size_t)(0 * HID + u) * BATCH];
        gf += p[(size_t)(1 * HID + u) * BATCH];
        gg += p[(size_t)(2 * HID + u) * BATCH];
        go += p[(size_t)(3 * HID + u) * BATCH];
    }
    float iv = 1.0f / (1.0f + __expf(-gi));
    float fv = 1.0f / (1.0f + __expf(-gf));
    float gv = tanhf(gg);
    float ov = 1.0f / (1.0f + __expf(-go));
    float cn = fv * c[g] + iv * gv;
    c[g] = cn;
    float hv = ov * tanhf(cn);
    // pack to B-fragment: k=u -> kt=u>>5, quad=(u&31)>>3, e=u&7; n=b -> nt=b>>4
    int kt = u >> 5, quad = (u & 31) >> 3, e = u & 7;
    int nt = b >> 4, lane = quad * 16 + (b & 15);
    hnext[((size_t)(kt * 4 + nt) * 64 + lane) * 8 + e] = (_Float16)hv;
}

// ---- final: out[b][t] = bout + sum_k h_{t+1}[k][b] * wout[k] ----
__global__ __launch_bounds__(256)
void k_yout(const half8* __restrict__ h_all, const float* __restrict__ wout,
            const float* __restrict__ bout, float* __restrict__ out, int steps) {
    __shared__ float red[256];
    int t = blockIdx.x >> 6, b = blockIdx.x & 63;
    int tid = threadIdx.x;
    int kt = tid >> 2, quad = tid & 3;
    int nt = b >> 4, lane = quad * 16 + (b & 15);
    half8 hv = h_all[(size_t)(t + 1) * HGRP + (size_t)(kt * 4 + nt) * 64 + lane];
    int k0 = kt * 32 + quad * 8;
    const float4* pw = (const float4*)(wout + k0);
    float4 w0 = pw[0], w1 = pw[1];
    float s = (float)hv[0] * w0.x + (float)hv[1] * w0.y + (float)hv[2] * w0.z +
              (float)hv[3] * w0.w + (float)hv[4] * w1.x + (float)hv[5] * w1.y +
              (float)hv[6] * w1.z + (float)hv[7] * w1.w;
    red[tid] = s;
    __syncthreads();
    for (int st = 128; st > 0; st >>= 1) {
        if (tid < st) red[tid] += red[tid + st];
        __syncthreads();
    }
    if (tid == 0) out[(size_t)b * steps + t] = red[0] + bout[0];
}

extern "C" void kernel_launch(void* const* d_in, const int* in_sizes, int n_in,
                              void* d_out, int out_size, void* d_ws, size_t ws_size,
                              hipStream_t stream) {
    const float* token = (const float*)d_in[0];
    const float* wih   = (const float*)d_in[2];
    const float* whh   = (const float*)d_in[3];
    const float* bih   = (const float*)d_in[4];
    const float* bhh   = (const float*)d_in[5];
    const float* wout  = (const float*)d_in[6];
    const float* bout  = (const float*)d_in[7];
    float* out = (float*)d_out;
    const int steps = out_size / BATCH;              // 30

    char* ws = (char*)d_ws;
    size_t off = 0;
    auto carve = [&](size_t bytes) -> void* {
        void* p = ws + off;
        off = (off + bytes + 255) & ~(size_t)255;
        return p;
    };
    half8* wsum_p = (half8*)carve((size_t)G4 * HID * 2);               // 33.5 MB
    half8* whh_p  = (half8*)carve((size_t)G4 * HID * 2);               // 33.5 MB
    half8* h_all  = (half8*)carve((size_t)(steps + 1) * HID * BATCH * 2); // 8 MB
    float* c      = (float*)carve((size_t)HID * BATCH * 4);            // 512 KB
    float* bsum   = (float*)carve((size_t)G4 * 4);
    size_t base = off;
    int KS = 2;
    while (KS > 1 && base + (size_t)KS * G4 * BATCH * 4 > ws_size) KS >>= 1;
    float* partial = (float*)carve((size_t)KS * G4 * BATCH * 4);       // 4.2 MB @ KS=2
    const int ktper = NKT / KS;

    k_pack_w<<<dim3(NMT, HID / PKK), dim3(256), 0, stream>>>(wih, whh, wsum_p, whh_p);
    k_init<<<dim3(HGRP / 256), dim3(256), 0, stream>>>(token, bih, bhh, h_all, c, bsum);

    for (int t = 0; t < steps; ++t) {
        const half8* Wp = (t == 0) ? whh_p : wsum_p;  // x=0 at t=0
        const half8* Hp = h_all + (size_t)t * HGRP;
        _Float16* hnext = (_Float16*)h_all + (size_t)(t + 1) * HID * BATCH;
        k_gemm<<<dim3(NMT, KS), dim3(256), 0, stream>>>(Wp, Hp, partial, ktper);
        k_point<<<dim3(HID * BATCH / 256), dim3(256), 0, stream>>>(
            partial, bsum, c, hnext, KS);
    }

    k_yout<<<dim3(steps * BATCH), dim3(256), 0, stream>>>(
        h_all, wout, bout, out, steps);
}